// Round 6
// baseline (528.376 us; speedup 1.0000x reference)
//
#include <hip/hip_runtime.h>
#include <hip/hip_bf16.h>
#include <cstdint>

// Problem constants
#define BATCH 2048
#define MF    40                 // num fields
#define DDIM  64                 // embedding dim
#define LDIM  128                // hidden size per CIN layer
#define ROWS  (BATCH * DDIM)     // 131072 (b,d) rows

typedef __attribute__((ext_vector_type(4)))  short    short4_t;
typedef __attribute__((ext_vector_type(8)))  short    short8;
typedef __attribute__((ext_vector_type(8)))  __bf16   bf16x8;
typedef __attribute__((ext_vector_type(4)))  float    floatx4;
typedef __attribute__((ext_vector_type(16))) float    floatx16;
typedef __attribute__((ext_vector_type(4)))  uint32_t uint4_t;

__device__ __forceinline__ unsigned short f32_to_bf16(float f) {
    union { float f; uint32_t u; } v; v.f = f;
    uint32_t u = v.u;
    uint32_t r = (u + 0x7fffu + ((u >> 16) & 1u)) >> 16;   // RNE
    return (unsigned short)r;
}

// scale two packed bf16 (one dword) by fp32 s, round-half-up, repack.
// 7 VALU ops: shl, and, 2x mul, 2x add, perm.
__device__ __forceinline__ uint32_t scale2(uint32_t w, float s) {
    float lo = __builtin_bit_cast(float, w << 16);
    float hi = __builtin_bit_cast(float, w & 0xffff0000u);
    uint32_t plo = __builtin_bit_cast(uint32_t, lo * s) + 0x8000u;
    uint32_t phi = __builtin_bit_cast(uint32_t, hi * s) + 0x8000u;
    // dst = [phi.b3, phi.b2, plo.b3, plo.b2]  (v_perm_b32: a=bytes7..4, b=3..0)
    return __builtin_amdgcn_perm(phi, plo, 0x07060302u);
}

__device__ __forceinline__ bf16x8 scale_frag(bf16x8 a, float s) {
    uint4_t w = __builtin_bit_cast(uint4_t, a);
    uint4_t r;
#pragma unroll
    for (int i = 0; i < 4; ++i) r[i] = scale2(w[i], s);
    return __builtin_bit_cast(bf16x8, r);
}

// ---------------------------------------------------------------------------
// W prep: swizzle W into exact B-fragment order (bf16 RNE, zero-padded h>=H):
//   Wt[m][kk][cb][lane][j] = W[m][ kk*16 + (lane>>5)*8 + j ][ cb*32 + (lane&31) ]
// ---------------------------------------------------------------------------
__global__ void k_wprep(const float* __restrict__ W, unsigned short* __restrict__ Wt,
                        int KK, int H) {
    int bi = blockIdx.x;                 // (m*KK + kk)*4 + cb
    int lane = threadIdx.x;
    int cb = bi & 3;
    int mkk = bi >> 2;
    int kk = mkk % KK, m = mkk / KK;
    int l = cb * 32 + (lane & 31);
    int hbase = kk * 16 + (lane >> 5) * 8;
    unsigned short o[8];
#pragma unroll
    for (int j = 0; j < 8; ++j) {
        int h = hbase + j;
        float v = (h < H) ? W[((size_t)m * H + h) * LDIM + l] : 0.f;
        o[j] = f32_to_bf16(v);
    }
    *(short8*)(Wt + ((size_t)bi * 64 + lane) * 8) = *(const short8*)o;
}

// ---------------------------------------------------------------------------
// Z-GEMM + fused column-sum. NO LDS, NO staging barriers.
//   out_acc[row,l] = sum_m ( s_m(row) * XK[row,:] ) @ W[m,:,:]   (bf16 MFMA)
// Scale folded into the A-operand: in A-layout every lane's 8 elements share
// one row, so s_m is a per-lane scalar -> z = bf16(s*xk) built in VALU, MFMA
// accumulates straight into acc (no P tile, no fp32 epilogue, no sc vectors).
// Register working set fits 256/wave: acc 128 + afrag 64 + bbuf 32 + misc.
// B-frags stream from global (Wt is fragment-ordered, L2-resident) through a
// D-deep register ring; D chosen so kk%D is m-independent (static indexing).
// One bare s_barrier per m bounds intra-block drift (L1 locality); there is
// no vmcnt(0) drain anywhere in the loop.
// ---------------------------------------------------------------------------
template <int KK, bool FIRST, int OFF, bool WRITEX>
__global__ __launch_bounds__(256, 2) void k_gemm(
    const float* __restrict__ x,               // fp32 [B][MF][DDIM]
    const unsigned short* __restrict__ Xprev,  // bf16 frag-layout (unused if FIRST)
    const unsigned short* __restrict__ Wt,     // bf16 [MF][KK][4][64][8]
    unsigned short* __restrict__ Xout,         // bf16 frag-layout (unused if !WRITEX)
    float* __restrict__ out)                   // fp32 [B][384]
{
    const int tid  = threadIdx.x;
    const int lane = tid & 63, wave = tid >> 6;
    const int hf   = lane >> 5, r31 = lane & 31;
    const int rowhalf = wave >> 1, colhalf = wave & 1;
    const int b = blockIdx.x * 2 + rowhalf;    // this wave's batch

    // ---- A fragments (XK), once: afrag[t][kk], A[row=r31+32t][k=hf*8+j] ----
    bf16x8 afrag[2][KK];
    if constexpr (FIRST) {
#pragma unroll
        for (int t = 0; t < 2; ++t)
#pragma unroll
            for (int kk = 0; kk < KK; ++kk) {
                unsigned short tmp[8];
#pragma unroll
                for (int j = 0; j < 8; ++j) {
                    int h = kk * 16 + hf * 8 + j;
                    float v = (h < MF) ? x[((size_t)b * MF + h) * DDIM + t * 32 + r31] : 0.f;
                    tmp[j] = f32_to_bf16(v);
                }
                afrag[t][kk] = __builtin_bit_cast(bf16x8, *(const short8*)tmp);
            }
    } else {
        const int g = r31 >> 3, hs = (r31 >> 2) & 1, ii = r31 & 3;
#pragma unroll
        for (int t = 0; t < 2; ++t) {
            int tile = b * 2 + t;
#pragma unroll
            for (int kk = 0; kk < KK; ++kk) {
                int k0  = kk * 16 + hf * 8;
                int cbk = k0 >> 5, rr = k0 & 31;
                const unsigned short* p =
                    Xprev + ((size_t)(((tile * 4 + cbk) * 4 + g) * 2 + hs) * 32 + rr) * 4 + ii;
                unsigned short tmp[8];
#pragma unroll
                for (int j = 0; j < 8; ++j) tmp[j] = p[(size_t)j * 4];
                afrag[t][kk] = __builtin_bit_cast(bf16x8, *(const short8*)tmp);
            }
        }
    }

    floatx16 acc[2][2] = {};   // [tile][cbp] — the ONLY accumulators

    const int cbg0 = colhalf * 2, cbg1 = colhalf * 2 + 1;
    auto ldg = [&](int flat, int cb) {     // global B-frag load, frag-ordered
        return __builtin_bit_cast(
            bf16x8, *(const short8*)(Wt + (((size_t)flat * 4 + cb) * 64 + lane) * 8));
    };

    constexpr int NST = MF * KK;
    constexpr int D = (KK % 4 == 0) ? 4 : KK;   // kk%D is m-independent

    // prime the B-frag register ring
    bf16x8 bbuf[D][2];
#pragma unroll
    for (int p = 0; p < D; ++p) { bbuf[p][0] = ldg(p, cbg0); bbuf[p][1] = ldg(p, cbg1); }

    // per-lane scale source: s_m(row=t*32+r31) = x[b][m][t*32+r31]
    const float* sb = x + (size_t)b * MF * DDIM + r31;
    float s0 = sb[0], s1 = sb[32];             // m = 0
    float sn0, sn1;

#pragma unroll 1
    for (int m = 0; m < MF; ++m) {
        __syncthreads();                        // bare s_barrier (no LDS): drift bound
        int mn = (m + 1 < MF) ? m + 1 : m;      // prefetch next m's scales
        sn0 = sb[(size_t)mn * DDIM];
        sn1 = sb[(size_t)mn * DDIM + 32];
#pragma unroll
        for (int kk = 0; kk < KK; ++kk) {
            const int slot = kk % D;
            bf16x8 z0 = scale_frag(afrag[0][kk], s0);
            bf16x8 z1 = scale_frag(afrag[1][kk], s1);
            acc[0][0] = __builtin_amdgcn_mfma_f32_32x32x16_bf16(z0, bbuf[slot][0], acc[0][0], 0, 0, 0);
            acc[0][1] = __builtin_amdgcn_mfma_f32_32x32x16_bf16(z0, bbuf[slot][1], acc[0][1], 0, 0, 0);
            acc[1][0] = __builtin_amdgcn_mfma_f32_32x32x16_bf16(z1, bbuf[slot][0], acc[1][0], 0, 0, 0);
            acc[1][1] = __builtin_amdgcn_mfma_f32_32x32x16_bf16(z1, bbuf[slot][1], acc[1][1], 0, 0, 0);
            int pf = m * KK + kk + D;
            if (pf > NST - 1) pf = NST - 1;     // clamp: harmless re-read of last frag
            bbuf[slot][0] = ldg(pf, cbg0);
            bbuf[slot][1] = ldg(pf, cbg1);
        }
        s0 = sn0; s1 = sn1;
    }

    // ---- store x_next in C-fragment layout (coalesced b64 stores) ----
    // C/D: col = r31, row = (j&3) + 8*(j>>2) + 4*hf (+32*tile)
    if constexpr (WRITEX) {
#pragma unroll
        for (int t = 0; t < 2; ++t) {
            int tile = b * 2 + t;
#pragma unroll
            for (int cbp = 0; cbp < 2; ++cbp) {
                int cb = colhalf * 2 + cbp;
#pragma unroll
                for (int g = 0; g < 4; ++g) {
                    unsigned short o[4];
#pragma unroll
                    for (int i = 0; i < 4; ++i) o[i] = f32_to_bf16(acc[t][cbp][g * 4 + i]);
                    *(short4_t*)(Xout +
                        ((size_t)(((tile * 4 + cb) * 4 + g) * 2 + hf) * 32 + r31) * 4) =
                        *(const short4_t*)o;
                }
            }
        }
    }

    // ---- fused ps: out[b][OFF + l] = sum_d acc (fp32, all 64 d in-wave) ----
#pragma unroll
    for (int cbp = 0; cbp < 2; ++cbp) {
        float v = 0.f;
#pragma unroll
        for (int j = 0; j < 16; ++j) v += acc[0][cbp][j] + acc[1][cbp][j];
        v += __shfl_xor(v, 32);                 // other hf: remaining rows
        if (hf == 0)
            out[(size_t)b * 384 + OFF + (colhalf * 2 + cbp) * 32 + r31] = v;
    }
}

// ---------------------------------------------------------------------------
extern "C" void kernel_launch(void* const* d_in, const int* in_sizes, int n_in,
                              void* d_out, int out_size, void* d_ws, size_t ws_size,
                              hipStream_t stream) {
    const float* x  = (const float*)d_in[0];
    const float* W0 = (const float*)d_in[1];
    const float* W1 = (const float*)d_in[2];
    const float* W2 = (const float*)d_in[3];
    float* out = (float*)d_out;

    char* ws = (char*)d_ws;
    size_t off = 0;
    auto alloc = [&](size_t bytes) -> void* {
        void* p = ws + off;
        off += (bytes + 255) & ~(size_t)255;
        return p;
    };
    unsigned short* W0t = (unsigned short*)alloc((size_t)MF * 3 * 2048 * 2);   // 0.5 MB
    unsigned short* W1t = (unsigned short*)alloc((size_t)MF * 8 * 2048 * 2);   // 1.3 MB
    unsigned short* W2t = (unsigned short*)alloc((size_t)MF * 8 * 2048 * 2);   // 1.3 MB
    unsigned short* X1p = (unsigned short*)alloc((size_t)ROWS * LDIM * 2);     // 33.5 MB
    unsigned short* X2p = (unsigned short*)alloc((size_t)ROWS * LDIM * 2);     // 33.5 MB

    k_wprep<<<MF * 3 * 4, 64, 0, stream>>>(W0, W0t, 3, 40);
    k_wprep<<<MF * 8 * 4, 64, 0, stream>>>(W1, W1t, 8, 128);
    k_wprep<<<MF * 8 * 4, 64, 0, stream>>>(W2, W2t, 8, 128);

    k_gemm<3, true,  0,   true ><<<ROWS / 128, 256, 0, stream>>>(x, nullptr, W0t, X1p, out);
    k_gemm<8, false, 128, true ><<<ROWS / 128, 256, 0, stream>>>(x, X1p,     W1t, X2p, out);
    k_gemm<8, false, 256, false><<<ROWS / 128, 256, 0, stream>>>(x, X2p,     W2t, X2p, out);
}

// Round 7
// 492.009 us; speedup vs baseline: 1.0739x; 1.0739x over previous
//
#include <hip/hip_runtime.h>
#include <hip/hip_bf16.h>
#include <cstdint>

// Problem constants
#define BATCH 2048
#define MF    40                 // num fields
#define DDIM  64                 // embedding dim
#define LDIM  128                // hidden size per CIN layer
#define ROWS  (BATCH * DDIM)     // 131072 (b,d) rows

typedef __attribute__((ext_vector_type(4)))  short    short4_t;
typedef __attribute__((ext_vector_type(8)))  short    short8;
typedef __attribute__((ext_vector_type(8)))  __bf16   bf16x8;
typedef __attribute__((ext_vector_type(16))) float    floatx16;
typedef __attribute__((ext_vector_type(4)))  uint32_t uint4_t;

__device__ __forceinline__ unsigned short f32_to_bf16(float f) {
    union { float f; uint32_t u; } v; v.f = f;
    uint32_t u = v.u;
    uint32_t r = (u + 0x7fffu + ((u >> 16) & 1u)) >> 16;   // RNE
    return (unsigned short)r;
}

// scale two packed bf16 (one dword) by fp32 s, round-half-up, repack.
// 7 VALU ops (proven correct in round 6).
__device__ __forceinline__ uint32_t scale2(uint32_t w, float s) {
    float lo = __builtin_bit_cast(float, w << 16);
    float hi = __builtin_bit_cast(float, w & 0xffff0000u);
    uint32_t plo = __builtin_bit_cast(uint32_t, lo * s) + 0x8000u;
    uint32_t phi = __builtin_bit_cast(uint32_t, hi * s) + 0x8000u;
    return __builtin_amdgcn_perm(phi, plo, 0x07060302u);
}

__device__ __forceinline__ bf16x8 scale_frag(bf16x8 a, float s) {
    uint4_t w = __builtin_bit_cast(uint4_t, a);
    uint4_t r;
#pragma unroll
    for (int i = 0; i < 4; ++i) r[i] = scale2(w[i], s);
    return __builtin_bit_cast(bf16x8, r);
}

// ---------------------------------------------------------------------------
// W prep: swizzle W into exact B-fragment order (bf16 RNE, zero-padded h>=H):
//   Wt[m][kk][cb][lane][j] = W[m][ kk*16 + (lane>>5)*8 + j ][ cb*32 + (lane&31) ]
// ---------------------------------------------------------------------------
__global__ void k_wprep(const float* __restrict__ W, unsigned short* __restrict__ Wt,
                        int KK, int H) {
    int bi = blockIdx.x;                 // (m*KK + kk)*4 + cb
    int lane = threadIdx.x;
    int cb = bi & 3;
    int mkk = bi >> 2;
    int kk = mkk % KK, m = mkk / KK;
    int l = cb * 32 + (lane & 31);
    int hbase = kk * 16 + (lane >> 5) * 8;
    unsigned short o[8];
#pragma unroll
    for (int j = 0; j < 8; ++j) {
        int h = hbase + j;
        float v = (h < H) ? W[((size_t)m * H + h) * LDIM + l] : 0.f;
        o[j] = f32_to_bf16(v);
    }
    *(short8*)(Wt + ((size_t)bi * 64 + lane) * 8) = *(const short8*)o;
}

// ---------------------------------------------------------------------------
// Z-GEMM, whole-L waves + LDS-staged B.
//   out_acc[row,l] = sum_m ( s_m(row) * XK[row,:] ) @ W[m,:,:]   (bf16 MFMA)
// Block = 256 thr = 4 waves; wave w owns batch (blockIdx*4 + w): 64 rows x
// ALL 128 cols. Grid = ROWS/256 = 512 = exactly 2 blocks/CU (one round).
//   - z = bf16(s_m * xk) built in VALU (per-lane scalar s in A-layout);
//     MFMA accumulates DIRECTLY into acc — no P tile, no fp32 epilogue.
//     Whole-L: one z feeds 8 MFMAs (VALU:MFMA ~0.35, was 0.87 in round 6).
//   - W[m] slab double-buffered in LDS via global_load_lds x16B; staging is
//     issued a full m-step (~4100cy) before its vmcnt wait -> no drain stall.
//   - B-frags stream LDS->reg through a 2-slot pair ring (2 cb/slot, static
//     indexing, one prefetch pair in flight per 4-MFMA step).
//   - acc: 128 AGPRs; afrag 64 + bbuf 32 + z 16 + misc fit in 128 arch VGPRs.
//   - Xout in C-frag layout; ps fused (in-reg sum + shfl_xor(32)).
// NOTE: (256,2) -> 256 unified regs/wave. (512,4) spilled catastrophically
// in round 3 — do not revisit.
// ---------------------------------------------------------------------------
template <int KK, bool FIRST, int OFF, bool WRITEX>
__global__ __launch_bounds__(256, 2) void k_gemm(
    const float* __restrict__ x,               // fp32 [B][MF][DDIM]
    const unsigned short* __restrict__ Xprev,  // bf16 frag-layout (unused if FIRST)
    const unsigned short* __restrict__ Wt,     // bf16 [MF][KK][4][64][8]
    unsigned short* __restrict__ Xout,         // bf16 frag-layout (unused if !WRITEX)
    float* __restrict__ out)                   // fp32 [B][384]
{
    __shared__ unsigned short slab[2][KK * 2048];

    const int tid  = threadIdx.x;
    const int lane = tid & 63, wave = tid >> 6;
    const int hf   = lane >> 5, r31 = lane & 31;
    const int b = blockIdx.x * 4 + wave;       // this wave's batch

    // ---- A fragments (XK), once: afrag[t][kk], A[row=r31+32t][k=hf*8+j] ----
    bf16x8 afrag[2][KK];
    if constexpr (FIRST) {
#pragma unroll
        for (int t = 0; t < 2; ++t)
#pragma unroll
            for (int kk = 0; kk < KK; ++kk) {
                unsigned short tmp[8];
#pragma unroll
                for (int j = 0; j < 8; ++j) {
                    int h = kk * 16 + hf * 8 + j;
                    float v = (h < MF) ? x[((size_t)b * MF + h) * DDIM + t * 32 + r31] : 0.f;
                    tmp[j] = f32_to_bf16(v);
                }
                afrag[t][kk] = __builtin_bit_cast(bf16x8, *(const short8*)tmp);
            }
    } else {
        const int g = r31 >> 3, hs = (r31 >> 2) & 1, ii = r31 & 3;
#pragma unroll
        for (int t = 0; t < 2; ++t) {
            int tile = b * 2 + t;
#pragma unroll
            for (int kk = 0; kk < KK; ++kk) {
                int k0  = kk * 16 + hf * 8;
                int cbk = k0 >> 5, rr = k0 & 31;
                const unsigned short* p =
                    Xprev + ((size_t)(((tile * 4 + cbk) * 4 + g) * 2 + hs) * 32 + rr) * 4 + ii;
                unsigned short tmp[8];
#pragma unroll
                for (int j = 0; j < 8; ++j) tmp[j] = p[(size_t)j * 4];
                afrag[t][kk] = __builtin_bit_cast(bf16x8, *(const short8*)tmp);
            }
        }
    }

    floatx16 acc[2][4] = {};   // [tile][cb] — direct MFMA accumulators (AGPR)

    auto stage = [&](int m, int buf) {
        const unsigned short* src = Wt + (size_t)m * (KK * 2048);
#pragma unroll
        for (int it = 0; it < KK; ++it) {
            int c = it * 256 + tid;                    // 16B chunk index
            __builtin_amdgcn_global_load_lds(
                (const __attribute__((address_space(1))) uint32_t*)(src + (size_t)c * 8),
                (__attribute__((address_space(3))) uint32_t*)(&slab[buf][(size_t)c * 8]),
                16, 0, 0);
        }
    };

    auto ldfrag = [&](const unsigned short* sl, int kk, int cb) {
        return __builtin_bit_cast(
            bf16x8, *(const short8*)(sl + ((size_t)(kk * 4 + cb) * 64 + lane) * 8));
    };

    // per-lane scale source: s_m(row=t*32+r31) = x[b][m][t*32+r31]
    const float* sb = x + (size_t)b * MF * DDIM + r31;
    float s0 = sb[0], s1 = sb[32];             // m = 0
    float sn0, sn1;

    constexpr int NS = 2 * KK;                 // steps: (kk, cb-pair)

    stage(0, 0);
#pragma unroll 1
    for (int m = 0; m < MF; ++m) {
        asm volatile("s_waitcnt vmcnt(0)" ::: "memory");   // slab[m&1] staged
        __syncthreads();
        int mn = (m + 1 < MF) ? m + 1 : m;                 // prefetch next scales
        sn0 = sb[(size_t)mn * DDIM];
        sn1 = sb[(size_t)mn * DDIM + 32];
        if (m + 1 < MF) stage(m + 1, (m + 1) & 1);         // overlaps whole m-step

        const unsigned short* sl = slab[m & 1];

        // prime the 2-slot pair ring: slot p <- (kk=0, pair p)
        bf16x8 bbuf[2][2];
#pragma unroll
        for (int p = 0; p < 2; ++p) {
            bbuf[p][0] = ldfrag(sl, 0, p * 2 + 0);
            bbuf[p][1] = ldfrag(sl, 0, p * 2 + 1);
        }

        bf16x8 z0, z1;
#pragma unroll
        for (int s = 0; s < NS; ++s) {
            const int kk = s >> 1, pr = s & 1, slot = s & 1;
            if (pr == 0) {
                z0 = scale_frag(afrag[0][kk], s0);
                z1 = scale_frag(afrag[1][kk], s1);
            }
            acc[0][pr * 2 + 0] = __builtin_amdgcn_mfma_f32_32x32x16_bf16(z0, bbuf[slot][0], acc[0][pr * 2 + 0], 0, 0, 0);
            acc[1][pr * 2 + 0] = __builtin_amdgcn_mfma_f32_32x32x16_bf16(z1, bbuf[slot][0], acc[1][pr * 2 + 0], 0, 0, 0);
            acc[0][pr * 2 + 1] = __builtin_amdgcn_mfma_f32_32x32x16_bf16(z0, bbuf[slot][1], acc[0][pr * 2 + 1], 0, 0, 0);
            acc[1][pr * 2 + 1] = __builtin_amdgcn_mfma_f32_32x32x16_bf16(z1, bbuf[slot][1], acc[1][pr * 2 + 1], 0, 0, 0);
            if (s + 2 < NS) {
                const int kn = (s + 2) >> 1, prn = (s + 2) & 1;
                bbuf[slot][0] = ldfrag(sl, kn, prn * 2 + 0);
                bbuf[slot][1] = ldfrag(sl, kn, prn * 2 + 1);
            }
        }
        s0 = sn0; s1 = sn1;
    }

    // ---- store x_next in C-fragment layout (coalesced b64 stores) ----
    // C/D: col = r31, row = (j&3) + 8*(j>>2) + 4*hf (+32*tile)
    if constexpr (WRITEX) {
#pragma unroll
        for (int t = 0; t < 2; ++t) {
            int tile = b * 2 + t;
#pragma unroll
            for (int cb = 0; cb < 4; ++cb) {
#pragma unroll
                for (int g = 0; g < 4; ++g) {
                    unsigned short o[4];
#pragma unroll
                    for (int i = 0; i < 4; ++i) o[i] = f32_to_bf16(acc[t][cb][g * 4 + i]);
                    *(short4_t*)(Xout +
                        ((size_t)(((tile * 4 + cb) * 4 + g) * 2 + hf) * 32 + r31) * 4) =
                        *(const short4_t*)o;
                }
            }
        }
    }

    // ---- fused ps: out[b][OFF + l] = sum_d acc (fp32, all 64 d in-wave) ----
#pragma unroll
    for (int cb = 0; cb < 4; ++cb) {
        float v = 0.f;
#pragma unroll
        for (int j = 0; j < 16; ++j) v += acc[0][cb][j] + acc[1][cb][j];
        v += __shfl_xor(v, 32);                 // other hf: remaining rows
        if (hf == 0)
            out[(size_t)b * 384 + OFF + cb * 32 + r31] = v;
    }
}

// ---------------------------------------------------------------------------
extern "C" void kernel_launch(void* const* d_in, const int* in_sizes, int n_in,
                              void* d_out, int out_size, void* d_ws, size_t ws_size,
                              hipStream_t stream) {
    const float* x  = (const float*)d_in[0];
    const float* W0 = (const float*)d_in[1];
    const float* W1 = (const float*)d_in[2];
    const float* W2 = (const float*)d_in[3];
    float* out = (float*)d_out;

    char* ws = (char*)d_ws;
    size_t off = 0;
    auto alloc = [&](size_t bytes) -> void* {
        void* p = ws + off;
        off += (bytes + 255) & ~(size_t)255;
        return p;
    };
    unsigned short* W0t = (unsigned short*)alloc((size_t)MF * 3 * 2048 * 2);   // 0.5 MB
    unsigned short* W1t = (unsigned short*)alloc((size_t)MF * 8 * 2048 * 2);   // 1.3 MB
    unsigned short* W2t = (unsigned short*)alloc((size_t)MF * 8 * 2048 * 2);   // 1.3 MB
    unsigned short* X1p = (unsigned short*)alloc((size_t)ROWS * LDIM * 2);     // 33.5 MB
    unsigned short* X2p = (unsigned short*)alloc((size_t)ROWS * LDIM * 2);     // 33.5 MB

    k_wprep<<<MF * 3 * 4, 64, 0, stream>>>(W0, W0t, 3, 40);
    k_wprep<<<MF * 8 * 4, 64, 0, stream>>>(W1, W1t, 8, 128);
    k_wprep<<<MF * 8 * 4, 64, 0, stream>>>(W2, W2t, 8, 128);

    k_gemm<3, true,  0,   true ><<<ROWS / 256, 256, 0, stream>>>(x, nullptr, W0t, X1p, out);
    k_gemm<8, false, 128, true ><<<ROWS / 256, 256, 0, stream>>>(x, X1p,     W1t, X2p, out);
    k_gemm<8, false, 256, false><<<ROWS / 256, 256, 0, stream>>>(x, X2p,     W2t, X2p, out);
}